// Round 3
// baseline (765.274 us; speedup 1.0000x reference)
//
#include <hip/hip_runtime.h>
#include <stdint.h>

#define GRAPHS 4096
#define NPG 18
#define EPERG 306
#define FIN 1536
#define BN_EPS 1e-5f
#define SLOPE 0.01f

using short8  = __attribute__((ext_vector_type(8))) short;
using ushort8 = __attribute__((ext_vector_type(8))) unsigned short;
using f32x4   = __attribute__((ext_vector_type(4))) float;

__device__ __forceinline__ unsigned short f2bf(float f) {
  unsigned u = __builtin_bit_cast(unsigned, f);
  u += 0x7fffu + ((u >> 16) & 1u);   // RNE to bf16 (inputs are finite)
  return (unsigned short)(u >> 16);
}

// ---------------------------------------------------------------------------
// Prep: (a) repack W1 (1536x32 f32) into bf16 MFMA B-fragment order:
//       frag[kstep(48)][ntile(2)][lane(64)][8]  with
//       n = ntile*16 + (lane&15), k = kstep*32 + (lane>>4)*8 + j
//       (b) fold bias+BN into per-channel alpha/beta for the 3 layers.
// ---------------------------------------------------------------------------
__global__ void prep_kernel(const float* __restrict__ W1,
    const float* __restrict__ b1, const float* __restrict__ g1,
    const float* __restrict__ be1, const float* __restrict__ rm1, const float* __restrict__ rv1,
    const float* __restrict__ b2, const float* __restrict__ g2,
    const float* __restrict__ be2, const float* __restrict__ rm2, const float* __restrict__ rv2,
    const float* __restrict__ b3, const float* __restrict__ g3,
    const float* __restrict__ be3, const float* __restrict__ rm3, const float* __restrict__ rv3,
    unsigned short* __restrict__ w1frag, float* __restrict__ ab) {
  const int tid = threadIdx.x;
  if (blockIdx.x < 24) {
    int slot = blockIdx.x * 256 + tid;            // [0, 6144)
    int L  = slot & 63;
    int nt = (slot >> 6) & 1;
    int ks = slot >> 7;
    int n  = nt * 16 + (L & 15);
    int kb = ks * 32 + ((L >> 4) << 3);
    ushort8 v;
#pragma unroll
    for (int j = 0; j < 8; ++j) v[j] = f2bf(W1[(kb + j) * 32 + n]);
    *((ushort8*)w1frag + slot) = v;
  } else {
    // ab layout: a1[0:32] b1[32:64] a2[64:128] b2[128:192] a3[192:320] b3[320:448]
    if (tid < 32) {
      float a = g1[tid] * rsqrtf(rv1[tid] + BN_EPS);
      ab[tid] = a; ab[32 + tid] = (b1[tid] - rm1[tid]) * a + be1[tid];
    }
    if (tid < 64) {
      float a = g2[tid] * rsqrtf(rv2[tid] + BN_EPS);
      ab[64 + tid] = a; ab[128 + tid] = (b2[tid] - rm2[tid]) * a + be2[tid];
    }
    if (tid < 128) {
      float a = g3[tid] * rsqrtf(rv3[tid] + BN_EPS);
      ab[192 + tid] = a; ab[320 + tid] = (b3[tid] - rm3[tid]) * a + be3[tid];
    }
  }
}

// ---------------------------------------------------------------------------
// Kernel A: P = bf16(x) @ bf16(W1)   [73728 x 1536] @ [1536 x 32] -> f32 P
// No LDS, no barriers. Each wave owns 16 rows; lane L's A-fragment for
// 16x16x32 MFMA is A[m=L&15][k=(L>>4)*8 + j] = 8 CONTIGUOUS floats of one
// row -> loaded directly from global as 2x dwordx4, converted in registers.
// B-fragments come prepacked from w1frag (L2-resident, 98 KB).
// ---------------------------------------------------------------------------
__global__ __launch_bounds__(256, 4) void gemm_xw1(
    const float* __restrict__ x, const unsigned short* __restrict__ w1frag,
    float* __restrict__ P) {
  const int tid  = threadIdx.x;
  const int lane = tid & 63;
  const int wv   = tid >> 6;
  const int rbase = (blockIdx.x * 4 + wv) * 16;
  const int r    = lane & 15;
  const int koff = (lane >> 4) << 3;

  const float* __restrict__ rowp = x + (size_t)(rbase + r) * FIN + koff;
  const short8* __restrict__ wf  = (const short8*)w1frag;

  f32x4 acc0 = {0.f, 0.f, 0.f, 0.f};
  f32x4 acc1 = {0.f, 0.f, 0.f, 0.f};

#pragma unroll 2
  for (int ks = 0; ks < 48; ++ks) {
    const float4* p = (const float4*)(rowp + ks * 32);
    float4 a0 = p[0], a1 = p[1];
    short8 b0 = wf[(ks * 2 + 0) * 64 + lane];
    short8 b1 = wf[(ks * 2 + 1) * 64 + lane];
    short8 af;
    af[0] = (short)f2bf(a0.x); af[1] = (short)f2bf(a0.y);
    af[2] = (short)f2bf(a0.z); af[3] = (short)f2bf(a0.w);
    af[4] = (short)f2bf(a1.x); af[5] = (short)f2bf(a1.y);
    af[6] = (short)f2bf(a1.z); af[7] = (short)f2bf(a1.w);
    acc0 = __builtin_amdgcn_mfma_f32_16x16x32_bf16(af, b0, acc0, 0, 0, 0);
    acc1 = __builtin_amdgcn_mfma_f32_16x16x32_bf16(af, b1, acc1, 0, 0, 0);
  }

  // C layout: col = lane&15, row = (lane>>4)*4 + q
  const int col = lane & 15;
  const int rq  = (lane >> 4) << 2;
  float* __restrict__ Pw = P + (size_t)(rbase + rq) * 32;
#pragma unroll
  for (int q = 0; q < 4; ++q) {
    Pw[q * 32 + col]      = acc0[q];
    Pw[q * 32 + 16 + col] = acc1[q];
  }
}

// ---------------------------------------------------------------------------
// Kernel B: per-graph epilogue. One block (256 thr) per 18-node graph.
// Dense normalized adjacency from edge weights, 3x (aggregate+BN+lrelu),
// layers 2/3 fp32 VALU with float4 W loads, mean-pool + MLP head.
// ---------------------------------------------------------------------------
__global__ __launch_bounds__(256, 4) void gcn_epilogue(
    const float* __restrict__ P, const float* __restrict__ ew,
    const float* __restrict__ W2, const float* __restrict__ W3,
    const float* __restrict__ fW1, const float* __restrict__ fb1,
    const float* __restrict__ fW2, const float* __restrict__ fb2,
    const float* __restrict__ fW3, const float* __restrict__ fb3,
    const float* __restrict__ fW4, const float* __restrict__ fb4,
    const float* __restrict__ ab, float* __restrict__ out) {
  const int g   = blockIdx.x;
  const int tid = threadIdx.x;

  __shared__ float ew_s[EPERG];
  __shared__ float dinv_s[NPG];
  __shared__ float An[NPG][NPG + 1];
  __shared__ __align__(16) float Pb[NPG][132];
  __shared__ __align__(16) float Hb[NPG][132];
  __shared__ float pooled[128];
  __shared__ float m1[64];
  __shared__ float m2[32];
  __shared__ float m3[16];

  // ---- stage 1: edge weights + P tile (18x32, contiguous 2304 B) -----------
  for (int i = tid; i < EPERG; i += 256) ew_s[i] = ew[g * EPERG + i];
  if (tid < 144) {
    int idx = tid * 4;                      // flat f32 index into 18x32 tile
    f32x4 v = *(const f32x4*)(P + (size_t)g * NPG * 32 + idx);
    *(f32x4*)&Pb[idx >> 5][idx & 31] = v;
  }
  __syncthreads();

  // ---- stage 2: degrees (self-loop weight 1 included) -----------------------
  if (tid < NPG) {
    float deg = 1.0f;
#pragma unroll
    for (int j = 0; j < 17; ++j) {
      int s = j + (j >= tid);
      deg += ew_s[s * 17 + (tid - (tid > s ? 1 : 0))];
    }
    dinv_s[tid] = rsqrtf(deg);
  }
  __syncthreads();

  // ---- stage 3: dense normalized adjacency (18x18) --------------------------
  for (int o = tid; o < NPG * NPG; o += 256) {
    int d = o / NPG, s = o - d * NPG;
    float v;
    if (d == s) v = dinv_s[d] * dinv_s[d];
    else        v = dinv_s[s] * ew_s[s * 17 + (d - (d > s ? 1 : 0))] * dinv_s[d];
    An[d][s] = v;
  }
  __syncthreads();

  // ---- stage 4: layer-1 aggregate + BN + lrelu ------------------------------
  if (tid < NPG * 8) {
    int d = tid >> 3, c4 = tid & 7;
    f32x4 s = {0.f, 0.f, 0.f, 0.f};
#pragma unroll
    for (int ss = 0; ss < NPG; ++ss) {
      float a = An[d][ss];
      const f32x4 p = *(const f32x4*)&Pb[ss][c4 * 4];
#pragma unroll
      for (int j = 0; j < 4; ++j) s[j] = fmaf(a, p[j], s[j]);
    }
    const f32x4 al = *(const f32x4*)(ab + c4 * 4);
    const f32x4 bt = *(const f32x4*)(ab + 32 + c4 * 4);
#pragma unroll
    for (int j = 0; j < 4; ++j) {
      float v = fmaf(s[j], al[j], bt[j]);
      Hb[d][c4 * 4 + j] = v >= 0.f ? v : SLOPE * v;
    }
  }
  __syncthreads();

  // ---- stage 5: layer-2 matmul (18x32 @ 32x64), float4 W loads --------------
  for (int o = tid; o < NPG * 16; o += 256) {
    int r = o >> 4, c4 = o & 15;
    f32x4 s = {0.f, 0.f, 0.f, 0.f};
#pragma unroll 8
    for (int k = 0; k < 32; ++k) {
      float h = Hb[r][k];
      const f32x4 w = *(const f32x4*)&W2[k * 64 + c4 * 4];
#pragma unroll
      for (int j = 0; j < 4; ++j) s[j] = fmaf(h, w[j], s[j]);
    }
    *(f32x4*)&Pb[r][c4 * 4] = s;
  }
  __syncthreads();
  for (int o = tid; o < NPG * 16; o += 256) {
    int d = o >> 4, c4 = o & 15;
    f32x4 s = {0.f, 0.f, 0.f, 0.f};
#pragma unroll
    for (int ss = 0; ss < NPG; ++ss) {
      float a = An[d][ss];
      const f32x4 p = *(const f32x4*)&Pb[ss][c4 * 4];
#pragma unroll
      for (int j = 0; j < 4; ++j) s[j] = fmaf(a, p[j], s[j]);
    }
    const f32x4 al = *(const f32x4*)(ab + 64 + c4 * 4);
    const f32x4 bt = *(const f32x4*)(ab + 128 + c4 * 4);
#pragma unroll
    for (int j = 0; j < 4; ++j) {
      float v = fmaf(s[j], al[j], bt[j]);
      Hb[d][c4 * 4 + j] = v >= 0.f ? v : SLOPE * v;
    }
  }
  __syncthreads();

  // ---- stage 6: layer-3 matmul (18x64 @ 64x128), float4 W loads -------------
  for (int o = tid; o < NPG * 32; o += 256) {
    int r = o >> 5, c4 = o & 31;
    f32x4 s = {0.f, 0.f, 0.f, 0.f};
#pragma unroll 8
    for (int k = 0; k < 64; ++k) {
      float h = Hb[r][k];
      const f32x4 w = *(const f32x4*)&W3[k * 128 + c4 * 4];
#pragma unroll
      for (int j = 0; j < 4; ++j) s[j] = fmaf(h, w[j], s[j]);
    }
    *(f32x4*)&Pb[r][c4 * 4] = s;
  }
  __syncthreads();
  for (int o = tid; o < NPG * 32; o += 256) {
    int d = o >> 5, c4 = o & 31;
    f32x4 s = {0.f, 0.f, 0.f, 0.f};
#pragma unroll
    for (int ss = 0; ss < NPG; ++ss) {
      float a = An[d][ss];
      const f32x4 p = *(const f32x4*)&Pb[ss][c4 * 4];
#pragma unroll
      for (int j = 0; j < 4; ++j) s[j] = fmaf(a, p[j], s[j]);
    }
    const f32x4 al = *(const f32x4*)(ab + 192 + c4 * 4);
    const f32x4 bt = *(const f32x4*)(ab + 320 + c4 * 4);
#pragma unroll
    for (int j = 0; j < 4; ++j) {
      float v = fmaf(s[j], al[j], bt[j]);
      Hb[d][c4 * 4 + j] = v >= 0.f ? v : SLOPE * v;
    }
  }
  __syncthreads();

  // ---- stage 7: mean pool + MLP head ---------------------------------------
  if (tid < 128) {
    float s = 0.f;
#pragma unroll
    for (int d = 0; d < NPG; ++d) s += Hb[d][tid];
    pooled[tid] = s * (1.0f / 18.0f);
  }
  __syncthreads();
  if (tid < 64) {
    float s = fb1[tid];
#pragma unroll 8
    for (int k = 0; k < 128; ++k) s = fmaf(pooled[k], fW1[k * 64 + tid], s);
    m1[tid] = s >= 0.f ? s : SLOPE * s;
  }
  __syncthreads();
  if (tid < 32) {
    float s = fb2[tid];
#pragma unroll
    for (int k = 0; k < 64; ++k) s = fmaf(m1[k], fW2[k * 32 + tid], s);
    m2[tid] = s >= 0.f ? s : SLOPE * s;
  }
  __syncthreads();
  if (tid < 16) {
    float s = fb3[tid];
#pragma unroll
    for (int k = 0; k < 32; ++k) s = fmaf(m2[k], fW3[k * 16 + tid], s);
    m3[tid] = s >= 0.f ? s : SLOPE * s;
  }
  __syncthreads();
  if (tid == 0) {
    float s = fb4[0];
#pragma unroll
    for (int k = 0; k < 16; ++k) s = fmaf(m3[k], fW4[k], s);
    out[g] = s;
  }
}

extern "C" void kernel_launch(void* const* d_in, const int* in_sizes, int n_in,
                              void* d_out, int out_size, void* d_ws, size_t ws_size,
                              hipStream_t stream) {
  (void)in_sizes; (void)n_in; (void)out_size; (void)ws_size;
  const float* x   = (const float*)d_in[0];
  const float* ew  = (const float*)d_in[2];
  const float* W1  = (const float*)d_in[4];
  const float* b1  = (const float*)d_in[5];
  const float* g1  = (const float*)d_in[6];
  const float* be1 = (const float*)d_in[7];
  const float* rm1 = (const float*)d_in[8];
  const float* rv1 = (const float*)d_in[9];
  const float* W2  = (const float*)d_in[10];
  const float* b2  = (const float*)d_in[11];
  const float* g2  = (const float*)d_in[12];
  const float* be2 = (const float*)d_in[13];
  const float* rm2 = (const float*)d_in[14];
  const float* rv2 = (const float*)d_in[15];
  const float* W3  = (const float*)d_in[16];
  const float* b3  = (const float*)d_in[17];
  const float* g3  = (const float*)d_in[18];
  const float* be3 = (const float*)d_in[19];
  const float* rv3 = (const float*)d_in[21];
  const float* rm3 = (const float*)d_in[20];
  const float* fW1 = (const float*)d_in[22];
  const float* fb1 = (const float*)d_in[23];
  const float* fW2 = (const float*)d_in[24];
  const float* fb2 = (const float*)d_in[25];
  const float* fW3 = (const float*)d_in[26];
  const float* fb3 = (const float*)d_in[27];
  const float* fW4 = (const float*)d_in[28];
  const float* fb4 = (const float*)d_in[29];

  unsigned short* w1frag = (unsigned short*)d_ws;            // 98304 B
  float* ab = (float*)((char*)d_ws + 98304);                 // 1792 B
  float* P  = (float*)((char*)d_ws + 98304 + 2048);          // 73728*32*4 B

  prep_kernel<<<25, 256, 0, stream>>>(W1, b1, g1, be1, rm1, rv1,
                                      b2, g2, be2, rm2, rv2,
                                      b3, g3, be3, rm3, rv3, w1frag, ab);
  gemm_xw1<<<GRAPHS * 18 / 64, 256, 0, stream>>>(x, w1frag, P);
  gcn_epilogue<<<GRAPHS, 256, 0, stream>>>(P, ew, W2, W3, fW1, fb1, fW2, fb2,
                                           fW3, fb3, fW4, fb4, ab,
                                           (float*)d_out);
}